// Round 5
// baseline (1285.695 us; speedup 1.0000x reference)
//
#include <hip/hip_runtime.h>

#define NPART 1024
#define NF    104      // 8 (tp0) + 32 (tp1) + 32 (tp2) + 32 (tp3)
#define CMS   161      // cm stride: pads LDS to 55168 B -> 2 blocks/CU ->
                       // backend VGPR budget 128 (empirical rule r1-r4:
                       // budget = 512 / LDS-implied waves-per-SIMD)

__device__ __forceinline__ float softplus_f(float v) {
    return __logf(1.0f + __expf(v));
}

// ---------------------------------------------------------------------------
// Fused pairwise kernel. Tile 32 rows x 64 cols, block 512 thr (8 waves).
// lane l = col; wave w (0..7); k-step 0..3: r = (l + 4w + k) & 31.
// LDS ds_add_f32 atomics (cm conflict-free; rs 2-way same-address).
// LDS deliberately padded to 55.2 KB: forces LDS-occupancy 2 blocks/CU so the
// backend allocates a 128-VGPR budget (r1 evidence); live set ~85 -> no spill.
// Epilogue: global atomicAdd into memset-zeroed Srow/Scol, scaled 1/1024.
// ---------------------------------------------------------------------------
__global__ __launch_bounds__(512) void pair_kernel(
    const float* __restrict__ x,
    const float* __restrict__ tw0, const float* __restrict__ tb0,
    const float* __restrict__ tw,  const float* __restrict__ tb,
    float* __restrict__ Srow,      // [1024][NF] means (pre-zeroed)
    float* __restrict__ Scol)      // [1024][NF] means (pre-zeroed)
{
    __shared__ float4 xs[32];
    __shared__ float rs[32][NF + 1];   // stride 105
    __shared__ float cm[64][CMS];      // stride 161 (LDS pad, see header)

    const int t = threadIdx.x;          // 0..511
    const int l = t & 63;               // lane = col within tile
    const int w = t >> 6;               // wave: 0..7
    const int rowTile = blockIdx.x;     // 0..31
    const int colTile = blockIdx.y;     // 0..15
    const int i0 = rowTile * 32;
    const int j  = colTile * 64 + l;

    for (int idx = t; idx < 32 * (NF + 1); idx += 512) ((float*)rs)[idx] = 0.0f;
    for (int idx = t; idx < 64 * CMS;      idx += 512) ((float*)cm)[idx] = 0.0f;
    if (t < 32) {
        xs[t] = make_float4(x[(i0 + t) * 3 + 0], x[(i0 + t) * 3 + 1],
                            x[(i0 + t) * 3 + 2], 0.0f);
    }
    __syncthreads();

    const float xj0 = x[j * 3 + 0];
    const float xj1 = x[j * 3 + 1];
    const float xj2 = x[j * 3 + 2];
    const float A = 0.62831853071795864769f;   // 2*pi / L, L = 10

    #pragma unroll 1
    for (int k = 0; k < 4; ++k) {
        const int r = (l + 4 * w + k) & 31;

        float4 xi = xs[r];
        float dx0 = xi.x - xj0;
        float dx1 = xi.y - xj1;
        float dx2 = xi.z - xj2;
        float s0 = __sinf(A * dx0), s1 = __sinf(A * dx1), s2 = __sinf(A * dx2);
        float c0 = __cosf(A * dx0), c1 = __cosf(A * dx1), c2 = __cosf(A * dx2);
        float mask = (i0 + r == j) ? 0.0f : 1.0f;
        float dsn = mask * sqrtf(s0 * s0 + s1 * s1 + s2 * s2);
        float dcs = mask * sqrtf(c0 * c0 + c1 * c1 + c2 * c2);
        float f0[8] = {c0, c1, c2, s0, s1, s2, dsn, dcs};

        #pragma unroll
        for (int q = 0; q < 8; ++q) {
            atomicAdd(&rs[r][q], f0[q]);      // ds_add_f32
            atomicAdd(&cm[l][q], f0[q]);
        }

        // ---- layer 1: 8 -> 32
        float2 acc[16];
        const float2* tb02 = (const float2*)tb0;
        #pragma unroll
        for (int o2 = 0; o2 < 16; ++o2) acc[o2] = tb02[o2];
        #pragma unroll
        for (int kk = 0; kk < 8; ++kk) {
            const float tv = f0[kk];
            const float2* w2 = (const float2*)(tw0 + kk * 32);
            #pragma unroll
            for (int o2 = 0; o2 < 16; ++o2) {
                acc[o2].x = fmaf(tv, w2[o2].x, acc[o2].x);
                acc[o2].y = fmaf(tv, w2[o2].y, acc[o2].y);
            }
        }
        float tp[32];
        #pragma unroll
        for (int o2 = 0; o2 < 16; ++o2) {
            tp[2 * o2]     = softplus_f(acc[o2].x);
            tp[2 * o2 + 1] = softplus_f(acc[o2].y);
        }
        #pragma unroll
        for (int o = 0; o < 32; ++o) {
            atomicAdd(&rs[r][8 + o], tp[o]);
            atomicAdd(&cm[l][8 + o], tp[o]);
        }

        // ---- layer 2: 32 -> 32, residual
        const float2* tb2 = (const float2*)tb;
        #pragma unroll
        for (int o2 = 0; o2 < 16; ++o2) acc[o2] = tb2[o2];
        #pragma unroll
        for (int kk = 0; kk < 32; ++kk) {
            const float tv = tp[kk];
            const float2* w2 = (const float2*)(tw + kk * 32);
            #pragma unroll
            for (int o2 = 0; o2 < 16; ++o2) {
                acc[o2].x = fmaf(tv, w2[o2].x, acc[o2].x);
                acc[o2].y = fmaf(tv, w2[o2].y, acc[o2].y);
            }
        }
        #pragma unroll
        for (int o2 = 0; o2 < 16; ++o2) {
            tp[2 * o2]     += softplus_f(acc[o2].x);
            tp[2 * o2 + 1] += softplus_f(acc[o2].y);
        }
        #pragma unroll
        for (int o = 0; o < 32; ++o) {
            atomicAdd(&rs[r][40 + o], tp[o]);
            atomicAdd(&cm[l][40 + o], tp[o]);
        }

        // ---- layer 3: 32 -> 32, residual
        #pragma unroll
        for (int o2 = 0; o2 < 16; ++o2) acc[o2] = tb2[16 + o2];
        #pragma unroll
        for (int kk = 0; kk < 32; ++kk) {
            const float tv = tp[kk];
            const float2* w2 = (const float2*)(tw + 1024 + kk * 32);
            #pragma unroll
            for (int o2 = 0; o2 < 16; ++o2) {
                acc[o2].x = fmaf(tv, w2[o2].x, acc[o2].x);
                acc[o2].y = fmaf(tv, w2[o2].y, acc[o2].y);
            }
        }
        #pragma unroll
        for (int o2 = 0; o2 < 16; ++o2) {
            tp[2 * o2]     += softplus_f(acc[o2].x);
            tp[2 * o2 + 1] += softplus_f(acc[o2].y);
        }
        #pragma unroll
        for (int o = 0; o < 32; ++o) {
            atomicAdd(&rs[r][72 + o], tp[o]);
            atomicAdd(&cm[l][72 + o], tp[o]);
        }
    }

    __syncthreads();
    const float sc = 1.0f / 1024.0f;
    for (int idx = t; idx < 32 * NF; idx += 512) {
        int rr = idx / NF, f = idx - rr * NF;
        atomicAdd(&Srow[(i0 + rr) * NF + f], rs[rr][f] * sc);
    }
    for (int idx = t; idx < 64 * NF; idx += 512) {
        int cc = idx / NF, f = idx - cc * NF;
        atomicAdd(&Scol[(colTile * 64 + cc) * NF + f], cm[cc][f] * sc);
    }
}

// layer 0: sp=0 so only tp0 mean features (W0 rows 9..24) contribute.
// Also emits up/dn partial sums of the produced sp into sums_out[0:64|64:128].
__global__ __launch_bounds__(256) void sp_layer0_kernel(
    const float* __restrict__ w0, const float* __restrict__ b0,
    const float* __restrict__ Srow, const float* __restrict__ Scol,
    float* __restrict__ sp, float* __restrict__ sums_out)
{
    int t = threadIdx.x;
    int r = blockIdx.x * 4 + (t >> 6);
    int o = t & 63;
    float a = b0[o];
    #pragma unroll
    for (int k = 0; k < 8; ++k) a = fmaf(Srow[r * NF + k], w0[(9 + k) * 64 + o], a);
    #pragma unroll
    for (int k = 0; k < 8; ++k) a = fmaf(Scol[r * NF + k], w0[(17 + k) * 64 + o], a);
    float v = softplus_f(a);
    sp[r * 64 + o] = v;
    atomicAdd(&sums_out[(r < 512 ? 0 : 64) + o], v);
}

// layers 1,2: sp_out = sp_in + softplus([sp,up,dn,trow,tcol] @ W + b).
// uvec (bias + up/dn-mean contributions) computed per block from sums_in.
// Emits next layer's up/dn partial sums into sums_out.
__global__ __launch_bounds__(256) void sp_layer_kernel(
    const float* __restrict__ spin, const float* __restrict__ W,
    const float* __restrict__ b, const float* __restrict__ sums_in,
    const float* __restrict__ Srow, const float* __restrict__ Scol,
    int F0, float* __restrict__ spout, float* __restrict__ sums_out)
{
    __shared__ float uv[64];
    int t = threadIdx.x;
    int o = t & 63;
    if (t < 64) {
        const float ns = 1.0f / 512.0f;
        float a2 = b[t];
        #pragma unroll 8
        for (int k = 0; k < 64; ++k) a2 = fmaf(sums_in[k] * ns, W[(64 + k) * 64 + t], a2);
        #pragma unroll 8
        for (int k = 0; k < 64; ++k) a2 = fmaf(sums_in[64 + k] * ns, W[(128 + k) * 64 + t], a2);
        uv[t] = a2;
    }
    __syncthreads();
    int r = blockIdx.x * 4 + (t >> 6);
    float a = uv[o];
    const float* sprow = spin + r * 64;
    #pragma unroll 8
    for (int k = 0; k < 64; ++k) a = fmaf(sprow[k], W[k * 64 + o], a);
    #pragma unroll 8
    for (int k = 0; k < 32; ++k) a = fmaf(Srow[r * NF + F0 + k], W[(192 + k) * 64 + o], a);
    #pragma unroll 8
    for (int k = 0; k < 32; ++k) a = fmaf(Scol[r * NF + F0 + k], W[(224 + k) * 64 + o], a);
    float v = sprow[o] + softplus_f(a);
    spout[r * 64 + o] = v;
    atomicAdd(&sums_out[(r < 512 ? 0 : 64) + o], v);
}

// final layer + fin projection + residual x
__global__ __launch_bounds__(256) void sp_final_kernel(
    const float* __restrict__ spin, const float* __restrict__ W,
    const float* __restrict__ b, const float* __restrict__ sums_in,
    const float* __restrict__ Srow, const float* __restrict__ Scol,
    const float* __restrict__ x, const float* __restrict__ finw, const float* __restrict__ finb,
    float* __restrict__ out)
{
    __shared__ float uv[64];
    __shared__ float sb[4][64];
    int t = threadIdx.x;
    int ty = t >> 6, o = t & 63;
    if (t < 64) {
        const float ns = 1.0f / 512.0f;
        float a2 = b[t];
        #pragma unroll 8
        for (int k = 0; k < 64; ++k) a2 = fmaf(sums_in[k] * ns, W[(64 + k) * 64 + t], a2);
        #pragma unroll 8
        for (int k = 0; k < 64; ++k) a2 = fmaf(sums_in[64 + k] * ns, W[(128 + k) * 64 + t], a2);
        uv[t] = a2;
    }
    __syncthreads();
    int r = blockIdx.x * 4 + ty;
    float a = uv[o];
    const float* sprow = spin + r * 64;
    #pragma unroll 8
    for (int k = 0; k < 64; ++k) a = fmaf(sprow[k], W[k * 64 + o], a);
    #pragma unroll 8
    for (int k = 0; k < 32; ++k) a = fmaf(Srow[r * NF + 72 + k], W[(192 + k) * 64 + o], a);
    #pragma unroll 8
    for (int k = 0; k < 32; ++k) a = fmaf(Scol[r * NF + 72 + k], W[(224 + k) * 64 + o], a);
    sb[ty][o] = sprow[o] + softplus_f(a);
    __syncthreads();
    if (t < 12) {
        int rr = t / 3, d = t - rr * 3;
        int row = blockIdx.x * 4 + rr;
        float acc = x[row * 3 + d] + finb[d];
        #pragma unroll
        for (int k = 0; k < 64; ++k) acc = fmaf(sb[rr][k], finw[k * 3 + d], acc);
        out[row * 3 + d] = acc;
    }
}

extern "C" void kernel_launch(void* const* d_in, const int* in_sizes, int n_in,
                              void* d_out, int out_size, void* d_ws, size_t ws_size,
                              hipStream_t stream)
{
    (void)in_sizes; (void)n_in; (void)out_size; (void)ws_size;
    const float* x     = (const float*)d_in[0];
    const float* sp_w0 = (const float*)d_in[1];
    const float* sp_b0 = (const float*)d_in[2];
    const float* sp_w  = (const float*)d_in[3];
    const float* sp_b  = (const float*)d_in[4];
    const float* tp_w0 = (const float*)d_in[5];
    const float* tp_b0 = (const float*)d_in[6];
    const float* tp_w  = (const float*)d_in[7];
    const float* tp_b  = (const float*)d_in[8];
    const float* fin_w = (const float*)d_in[9];
    const float* fin_b = (const float*)d_in[10];
    float* out = (float*)d_out;
    float* ws  = (float*)d_ws;

    float* Srow  = ws;                      // 1024*NF (means)
    float* Scol  = Srow + NPART * NF;       // 1024*NF (means)
    float* sums0 = Scol + NPART * NF;       // 128 (up|dn sums after layer0)
    float* sums1 = sums0 + 128;             // 128
    float* sums2 = sums1 + 128;             // 128
    float* spA   = sums2 + 128;             // 1024*64
    float* spB   = spA + NPART * 64;        // 1024*64
    float* spC   = spB + NPART * 64;        // 1024*64

    // zero Srow, Scol, sums0..2 in one memset
    hipMemsetAsync(Srow, 0, (2 * NPART * NF + 384) * sizeof(float), stream);

    pair_kernel<<<dim3(32, 16), 512, 0, stream>>>(x, tp_w0, tp_b0, tp_w, tp_b, Srow, Scol);
    sp_layer0_kernel<<<256, 256, 0, stream>>>(sp_w0, sp_b0, Srow, Scol, spA, sums0);
    sp_layer_kernel<<<256, 256, 0, stream>>>(spA, sp_w + 0 * 256 * 64, sp_b + 0 * 64,
                                             sums0, Srow, Scol, 8, spB, sums1);
    sp_layer_kernel<<<256, 256, 0, stream>>>(spB, sp_w + 1 * 256 * 64, sp_b + 1 * 64,
                                             sums1, Srow, Scol, 40, spC, sums2);
    sp_final_kernel<<<256, 256, 0, stream>>>(spC, sp_w + 2 * 256 * 64, sp_b + 2 * 64,
                                             sums2, Srow, Scol, x, fin_w, fin_b, out);
}